// Round 5
// baseline (457.691 us; speedup 1.0000x reference)
//
#include <hip/hip_runtime.h>
#include <stdint.h>

#define MDIM 8192
#define NDIM 4096
#define KDIM 4096
#define QBLK 128
#define KB 32   // KDIM / QBLK
#define NB 32   // NDIM / QBLK

#define BM 128
#define BN 128
#define BK 128
#define TILEB (BM * BK)   // 16384 bytes per tile buffer

typedef __attribute__((ext_vector_type(4))) int int32x4;

#define GPTR(p) ((const __attribute__((address_space(1))) void*)(p))
#define LPTR(p) ((__attribute__((address_space(3))) void*)(p))

__device__ __forceinline__ int quant1(float v, float s) {
  float q = rintf(v / s);
  q = fminf(fmaxf(q, -127.f), 127.f);
  return (int)q;
}

// ---------------- activation quant: one wave per (row m, k-block kb) ----------
// writes xq and transposed scales xsT[kb][m] (gemm stages these to LDS)
__global__ __launch_bounds__(256) void quant_x_kernel(
    const float* __restrict__ x, int8_t* __restrict__ xq, float* __restrict__ xsT) {
  const int lane = threadIdx.x & 63;
  const int wid = blockIdx.x * 4 + (threadIdx.x >> 6);
  const int m = wid >> 5;    // / KB
  const int kb = wid & 31;   // % KB
  const size_t base = (size_t)m * KDIM + (size_t)kb * QBLK;
  const float2 v = *reinterpret_cast<const float2*>(x + base + lane * 2);
  float amax = fmaxf(fabsf(v.x), fabsf(v.y));
#pragma unroll
  for (int off = 32; off; off >>= 1)
    amax = fmaxf(amax, __shfl_xor(amax, off));
  const float scale = fmaxf(amax / 127.0f, 1e-12f);
  const int ia = quant1(v.x, scale);
  const int ib = quant1(v.y, scale);
  const uint16_t packed = (uint16_t)((ia & 0xff) | ((ib & 0xff) << 8));
  *reinterpret_cast<uint16_t*>(xq + base + lane * 2) = packed;
  if (lane == 0) xsT[(size_t)kb * MDIM + m] = scale;
}

// ---------------- weight quant: one 256-thread block per 128x128 block --------
__global__ __launch_bounds__(256) void quant_w_kernel(
    const float* __restrict__ w, int8_t* __restrict__ wq, float* __restrict__ ws) {
  const int nb = blockIdx.x >> 5;   // / KB
  const int kb = blockIdx.x & 31;   // % KB
  const int tid = threadIdx.x;
  const int lane = tid & 63;
  const int wv = tid >> 6;
  __shared__ float red[4];

  float amax = 0.f;
  float4 vals[16];
#pragma unroll
  for (int i = 0; i < 16; ++i) {
    const int idx4 = tid + i * 256;         // 4096 float4 per block
    const int row = idx4 >> 5;
    const int c4 = idx4 & 31;
    const float4 v = *reinterpret_cast<const float4*>(
        w + (size_t)(nb * QBLK + row) * KDIM + (size_t)kb * QBLK + c4 * 4);
    vals[i] = v;
    amax = fmaxf(amax, fmaxf(fmaxf(fabsf(v.x), fabsf(v.y)),
                             fmaxf(fabsf(v.z), fabsf(v.w))));
  }
#pragma unroll
  for (int off = 32; off; off >>= 1)
    amax = fmaxf(amax, __shfl_xor(amax, off));
  if (lane == 0) red[wv] = amax;
  __syncthreads();
  amax = fmaxf(fmaxf(red[0], red[1]), fmaxf(red[2], red[3]));
  const float scale = fmaxf(amax / 127.0f, 1e-12f);

#pragma unroll
  for (int i = 0; i < 16; ++i) {
    const int idx4 = tid + i * 256;
    const int row = idx4 >> 5;
    const int c4 = idx4 & 31;
    const float4 v = vals[i];
    const int qa = quant1(v.x, scale);
    const int qb = quant1(v.y, scale);
    const int qc = quant1(v.z, scale);
    const int qd = quant1(v.w, scale);
    const uint32_t packed = (uint32_t)(qa & 0xff) | ((uint32_t)(qb & 0xff) << 8) |
                            ((uint32_t)(qc & 0xff) << 16) | ((uint32_t)(qd & 0xff) << 24);
    *reinterpret_cast<uint32_t*>(
        wq + (size_t)(nb * QBLK + row) * KDIM + (size_t)kb * QBLK + c4 * 4) = packed;
  }
  if (tid == 0) ws[nb * KB + kb] = scale;
}

// ---------------- int8 blockwise GEMM, 2-phase counted-vmcnt pipeline --------
// LDS A/B tiles XOR-swizzled on 16B chunks (linear LDS dest + inverse-swizzled
// global source; swizzled ds_read). MFMA i32_16x16x64_i8.
// Schedule per kb: STAGE(kb+1) -> s_waitcnt vmcnt(8) (stage kb landed; kb+1's
// 8 loads stay in flight) -> raw s_barrier -> COMPUTE(kb) -> raw s_barrier.
// NO vmcnt(0) in the main loop; all compute-phase operands (scales) come from
// LDS so no compiler-inserted VMEM drains appear inside COMPUTE.
__global__ __launch_bounds__(256) void gemm_i8_kernel(
    const int8_t* __restrict__ Aq, const int8_t* __restrict__ Bq,
    const float* __restrict__ xsT, const float* __restrict__ wsp,
    const float* __restrict__ bias, float* __restrict__ C) {
  __shared__ int8_t As[2 * TILEB];      // 32 KB, swizzled
  __shared__ int8_t Bs[2 * TILEB];      // 32 KB, swizzled
  __shared__ float xsl[KB * BM];        // 16 KB: xs[row,kb]*ws[nb,kb]

  const int tid = threadIdx.x;
  const int lane = tid & 63;
  const int wv = tid >> 6;
  const int wr = wv >> 1;       // wave row 0..1
  const int wc = wv & 1;        // wave col 0..1
  const int l15 = lane & 15;
  const int lhi = lane >> 4;

  const int tiles_n = NDIM / BN;          // 32
  const int bm = blockIdx.x / tiles_n;
  const int bn = blockIdx.x % tiles_n;
  const int brow = bm * BM;
  const int bcol = bn * BN;

  float accf[4][4][4];
#pragma unroll
  for (int m = 0; m < 4; ++m)
#pragma unroll
    for (int n = 0; n < 4; ++n)
#pragma unroll
      for (int r = 0; r < 4; ++r) accf[m][n][r] = 0.f;

  const int32x4 zeroc = {0, 0, 0, 0};

  const int8_t* arow = Aq + (size_t)brow * KDIM;
  const int8_t* brp = Bq + (size_t)bcol * KDIM;

  // staging addresses (loop-invariant parts)
  const int soff = tid * 16;                 // 0..4080
  const int sr = soff >> 7;                  // row 0..31 (per 256-thread slab)
  const int sc = (soff >> 4) & 7;
  const int scsrc = (sc ^ (sr & 7)) * 16;

#define STAGE(buf, kb)                                                          \
  {                                                                             \
    const int k0_ = (kb) * BK;                                                  \
    _Pragma("unroll") for (int i = 0; i < 4; ++i) {                             \
      const int r_ = sr + i * 32;                                               \
      __builtin_amdgcn_global_load_lds(                                         \
          GPTR(arow + (size_t)r_ * KDIM + k0_ + scsrc),                         \
          LPTR(As + (buf) * TILEB + i * 4096 + soff), 16, 0, 0);                \
    }                                                                           \
    _Pragma("unroll") for (int i = 0; i < 4; ++i) {                             \
      const int r_ = sr + i * 32;                                               \
      __builtin_amdgcn_global_load_lds(                                         \
          GPTR(brp + (size_t)r_ * KDIM + k0_ + scsrc),                          \
          LPTR(Bs + (buf) * TILEB + i * 4096 + soff), 16, 0, 0);                \
    }                                                                           \
  }

#define COMPUTE(buf, kb)                                                        \
  {                                                                             \
    const int8_t* asb_ = As + (buf) * TILEB;                                    \
    const int8_t* bsb_ = Bs + (buf) * TILEB;                                    \
    int32x4 acci[4][4];                                                         \
    _Pragma("unroll") for (int kk = 0; kk < 2; ++kk) {                          \
      const int cl_ = kk * 4 + lhi;                                             \
      int32x4 af[4], bf[4];                                                     \
      _Pragma("unroll") for (int m = 0; m < 4; ++m) {                           \
        const int rowA_ = wr * 64 + m * 16 + l15;                               \
        af[m] = *reinterpret_cast<const int32x4*>(                              \
            asb_ + rowA_ * 128 + ((cl_ ^ (rowA_ & 7)) * 16));                   \
      }                                                                         \
      _Pragma("unroll") for (int n = 0; n < 4; ++n) {                           \
        const int rowB_ = wc * 64 + n * 16 + l15;                               \
        bf[n] = *reinterpret_cast<const int32x4*>(                              \
            bsb_ + rowB_ * 128 + ((cl_ ^ (rowB_ & 7)) * 16));                   \
      }                                                                         \
      __builtin_amdgcn_s_setprio(1);                                            \
      if (kk == 0) {                                                            \
        _Pragma("unroll") for (int m = 0; m < 4; ++m)                           \
            _Pragma("unroll") for (int n = 0; n < 4; ++n)                       \
                acci[m][n] = __builtin_amdgcn_mfma_i32_16x16x64_i8(             \
                    af[m], bf[n], zeroc, 0, 0, 0);                              \
      } else {                                                                  \
        _Pragma("unroll") for (int m = 0; m < 4; ++m)                           \
            _Pragma("unroll") for (int n = 0; n < 4; ++n)                       \
                acci[m][n] = __builtin_amdgcn_mfma_i32_16x16x64_i8(             \
                    af[m], bf[n], acci[m][n], 0, 0, 0);                         \
      }                                                                         \
      __builtin_amdgcn_s_setprio(0);                                            \
    }                                                                           \
    _Pragma("unroll") for (int m = 0; m < 4; ++m) {                             \
      const float4 sx4_ = *reinterpret_cast<const float4*>(                     \
          xsl + (kb) * BM + wr * 64 + m * 16 + lhi * 4);                        \
      _Pragma("unroll") for (int r = 0; r < 4; ++r) {                           \
        const float sx_ = ((const float*)&sx4_)[r];                             \
        _Pragma("unroll") for (int n = 0; n < 4; ++n)                           \
            accf[m][n][r] += (float)acci[m][n][r] * sx_;                        \
      }                                                                         \
    }                                                                           \
  }

  // prologue: stage tile 0 and the pre-multiplied scale table; one full drain
  STAGE(0, 0);
#pragma unroll
  for (int i = 0; i < 4; ++i) {
    const int idx = i * 256 + tid;       // 1024 float4 chunks = 32 kb x 128 rows
    const int c = idx >> 5;              // kb index
    const int r4 = idx & 31;             // float4 group within the 128 rows
    float4 v = *reinterpret_cast<const float4*>(
        xsT + (size_t)c * MDIM + brow + r4 * 4);
    const float swc = wsp[bn * KB + c];
    v.x *= swc; v.y *= swc; v.z *= swc; v.w *= swc;
    *reinterpret_cast<float4*>(xsl + c * BM + r4 * 4) = v;
  }
  __syncthreads();

  for (int kb = 0; kb < KB - 1; ++kb) {
    const int cur = kb & 1;
    STAGE(cur ^ 1, kb + 1);
    asm volatile("s_waitcnt vmcnt(8)" ::: "memory");
    __builtin_amdgcn_s_barrier();
    asm volatile("" ::: "memory");
    COMPUTE(cur, kb);
    asm volatile("" ::: "memory");
    __builtin_amdgcn_s_barrier();
    asm volatile("" ::: "memory");
  }
  asm volatile("s_waitcnt vmcnt(0)" ::: "memory");
  __builtin_amdgcn_s_barrier();
  asm volatile("" ::: "memory");
  COMPUTE((KB - 1) & 1, KB - 1);

  // epilogue: bias + store f32
#pragma unroll
  for (int m = 0; m < 4; ++m) {
#pragma unroll
    for (int r = 0; r < 4; ++r) {
      const int row = brow + wr * 64 + m * 16 + lhi * 4 + r;
#pragma unroll
      for (int n = 0; n < 4; ++n) {
        const int col = bcol + wc * 64 + n * 16 + l15;
        C[(size_t)row * NDIM + col] = accf[m][n][r] + bias[col];
      }
    }
  }
#undef STAGE
#undef COMPUTE
}

extern "C" void kernel_launch(void* const* d_in, const int* in_sizes, int n_in,
                              void* d_out, int out_size, void* d_ws, size_t ws_size,
                              hipStream_t stream) {
  const float* x = (const float*)d_in[0];
  const float* w = (const float*)d_in[1];
  const float* bias = (const float*)d_in[2];
  float* out = (float*)d_out;

  char* base = (char*)d_ws;
  size_t off = 0;
  int8_t* xq = (int8_t*)(base + off); off += (size_t)MDIM * KDIM;          // 32 MB
  int8_t* wq = (int8_t*)(base + off); off += (size_t)NDIM * KDIM;          // 16 MB
  float* xsT = (float*)(base + off); off += (size_t)KB * MDIM * 4;         // 1 MB
  float* wsc = (float*)(base + off);                                       // 4 KB

  quant_x_kernel<<<(MDIM * KB) / 4, 256, 0, stream>>>(x, xq, xsT);
  quant_w_kernel<<<NB * KB, 256, 0, stream>>>(w, wq, wsc);
  gemm_i8_kernel<<<(MDIM / BM) * (NDIM / BN), 256, 0, stream>>>(xq, wq, xsT, wsc, bias, out);
}

// Round 6
// 280.014 us; speedup vs baseline: 1.6345x; 1.6345x over previous
//
#include <hip/hip_runtime.h>
#include <stdint.h>

#define MDIM 8192
#define NDIM 4096
#define KDIM 4096
#define QBLK 128
#define KB 32   // KDIM / QBLK
#define NB 32   // NDIM / QBLK

#define BM 128
#define BN 128
#define BK 128
#define TILEB (BM * BK)   // 16384 bytes per tile buffer

typedef __attribute__((ext_vector_type(4))) int int32x4;

#define GPTR(p) ((const __attribute__((address_space(1))) void*)(p))
#define LPTR(p) ((__attribute__((address_space(3))) void*)(p))

__device__ __forceinline__ int quant1(float v, float s) {
  float q = rintf(v / s);
  q = fminf(fmaxf(q, -127.f), 127.f);
  return (int)q;
}

// ---------------- activation quant: one wave per (row m, k-block kb) ----------
__global__ __launch_bounds__(256) void quant_x_kernel(
    const float* __restrict__ x, int8_t* __restrict__ xq, float* __restrict__ xsT) {
  const int lane = threadIdx.x & 63;
  const int wid = blockIdx.x * 4 + (threadIdx.x >> 6);
  const int m = wid >> 5;    // / KB
  const int kb = wid & 31;   // % KB
  const size_t base = (size_t)m * KDIM + (size_t)kb * QBLK;
  const float2 v = *reinterpret_cast<const float2*>(x + base + lane * 2);
  float amax = fmaxf(fabsf(v.x), fabsf(v.y));
#pragma unroll
  for (int off = 32; off; off >>= 1)
    amax = fmaxf(amax, __shfl_xor(amax, off));
  const float scale = fmaxf(amax / 127.0f, 1e-12f);
  const int ia = quant1(v.x, scale);
  const int ib = quant1(v.y, scale);
  const uint16_t packed = (uint16_t)((ia & 0xff) | ((ib & 0xff) << 8));
  *reinterpret_cast<uint16_t*>(xq + base + lane * 2) = packed;
  if (lane == 0) xsT[(size_t)kb * MDIM + m] = scale;
}

// ---------------- weight quant: one 256-thread block per 128x128 block --------
__global__ __launch_bounds__(256) void quant_w_kernel(
    const float* __restrict__ w, int8_t* __restrict__ wq, float* __restrict__ ws) {
  const int nb = blockIdx.x >> 5;   // / KB
  const int kb = blockIdx.x & 31;   // % KB
  const int tid = threadIdx.x;
  const int lane = tid & 63;
  const int wv = tid >> 6;
  __shared__ float red[4];

  float amax = 0.f;
  float4 vals[16];
#pragma unroll
  for (int i = 0; i < 16; ++i) {
    const int idx4 = tid + i * 256;         // 4096 float4 per block
    const int row = idx4 >> 5;
    const int c4 = idx4 & 31;
    const float4 v = *reinterpret_cast<const float4*>(
        w + (size_t)(nb * QBLK + row) * KDIM + (size_t)kb * QBLK + c4 * 4);
    vals[i] = v;
    amax = fmaxf(amax, fmaxf(fmaxf(fabsf(v.x), fabsf(v.y)),
                             fmaxf(fabsf(v.z), fabsf(v.w))));
  }
#pragma unroll
  for (int off = 32; off; off >>= 1)
    amax = fmaxf(amax, __shfl_xor(amax, off));
  if (lane == 0) red[wv] = amax;
  __syncthreads();
  amax = fmaxf(fmaxf(red[0], red[1]), fmaxf(red[2], red[3]));
  const float scale = fmaxf(amax / 127.0f, 1e-12f);

#pragma unroll
  for (int i = 0; i < 16; ++i) {
    const int idx4 = tid + i * 256;
    const int row = idx4 >> 5;
    const int c4 = idx4 & 31;
    const float4 v = vals[i];
    const int qa = quant1(v.x, scale);
    const int qb = quant1(v.y, scale);
    const int qc = quant1(v.z, scale);
    const int qd = quant1(v.w, scale);
    const uint32_t packed = (uint32_t)(qa & 0xff) | ((uint32_t)(qb & 0xff) << 8) |
                            ((uint32_t)(qc & 0xff) << 16) | ((uint32_t)(qd & 0xff) << 24);
    *reinterpret_cast<uint32_t*>(
        wq + (size_t)(nb * QBLK + row) * KDIM + (size_t)kb * QBLK + c4 * 4) = packed;
  }
  if (tid == 0) ws[nb * KB + kb] = scale;
}

// ---------------- int8 blockwise GEMM, minimum-2-phase pipeline --------------
// Catalog T3 "minimum 2-phase": per tile
//   STAGE(buf^1, t+1)  ->  COMPUTE(buf, t)  ->  s_waitcnt vmcnt(0)  ->  s_barrier
// One barrier per tile; the drain sits AFTER compute so the 8 in-flight stage
// loads hide under the MFMA+fixup phase. All compute-phase operands come from
// LDS (premultiplied scale table) so the loop is VMEM-pure.
__global__ __launch_bounds__(256) void gemm_i8_kernel(
    const int8_t* __restrict__ Aq, const int8_t* __restrict__ Bq,
    const float* __restrict__ xsT, const float* __restrict__ wsp,
    const float* __restrict__ bias, float* __restrict__ C) {
  __shared__ int8_t As[2 * TILEB];      // 32 KB, swizzled
  __shared__ int8_t Bs[2 * TILEB];      // 32 KB, swizzled
  __shared__ float xsl[KB * BM];        // 16 KB: xs[row,kb]*ws[nb,kb]

  const int tid = threadIdx.x;
  const int lane = tid & 63;
  const int wv = tid >> 6;
  const int wr = wv >> 1;       // wave row 0..1
  const int wc = wv & 1;        // wave col 0..1
  const int l15 = lane & 15;
  const int lhi = lane >> 4;

  const int tiles_n = NDIM / BN;          // 32
  const int bm = blockIdx.x / tiles_n;
  const int bn = blockIdx.x % tiles_n;
  const int brow = bm * BM;
  const int bcol = bn * BN;

  float accf[4][4][4];
#pragma unroll
  for (int m = 0; m < 4; ++m)
#pragma unroll
    for (int n = 0; n < 4; ++n)
#pragma unroll
      for (int r = 0; r < 4; ++r) accf[m][n][r] = 0.f;

  const int32x4 zeroc = {0, 0, 0, 0};

  const int8_t* arow = Aq + (size_t)brow * KDIM;
  const int8_t* brp = Bq + (size_t)bcol * KDIM;

  // staging addresses (loop-invariant parts)
  const int soff = tid * 16;                 // 0..4080
  const int sr = soff >> 7;                  // row 0..31 (per 256-thread slab)
  const int sc = (soff >> 4) & 7;
  const int scsrc = (sc ^ (sr & 7)) * 16;

#define STAGE(buf, kb)                                                          \
  {                                                                             \
    const int k0_ = (kb) * BK;                                                  \
    _Pragma("unroll") for (int i = 0; i < 4; ++i) {                             \
      const int r_ = sr + i * 32;                                               \
      __builtin_amdgcn_global_load_lds(                                         \
          GPTR(arow + (size_t)r_ * KDIM + k0_ + scsrc),                         \
          LPTR(As + (buf) * TILEB + i * 4096 + soff), 16, 0, 0);                \
    }                                                                           \
    _Pragma("unroll") for (int i = 0; i < 4; ++i) {                             \
      const int r_ = sr + i * 32;                                               \
      __builtin_amdgcn_global_load_lds(                                         \
          GPTR(brp + (size_t)r_ * KDIM + k0_ + scsrc),                          \
          LPTR(Bs + (buf) * TILEB + i * 4096 + soff), 16, 0, 0);                \
    }                                                                           \
  }

#define COMPUTE(buf, kb)                                                        \
  {                                                                             \
    const int8_t* asb_ = As + (buf) * TILEB;                                    \
    const int8_t* bsb_ = Bs + (buf) * TILEB;                                    \
    int32x4 acci[4][4];                                                         \
    _Pragma("unroll") for (int kk = 0; kk < 2; ++kk) {                          \
      const int cl_ = kk * 4 + lhi;                                             \
      int32x4 af[4], bf[4];                                                     \
      _Pragma("unroll") for (int m = 0; m < 4; ++m) {                           \
        const int rowA_ = wr * 64 + m * 16 + l15;                               \
        af[m] = *reinterpret_cast<const int32x4*>(                              \
            asb_ + rowA_ * 128 + ((cl_ ^ (rowA_ & 7)) * 16));                   \
      }                                                                         \
      _Pragma("unroll") for (int n = 0; n < 4; ++n) {                           \
        const int rowB_ = wc * 64 + n * 16 + l15;                               \
        bf[n] = *reinterpret_cast<const int32x4*>(                              \
            bsb_ + rowB_ * 128 + ((cl_ ^ (rowB_ & 7)) * 16));                   \
      }                                                                         \
      if (kk == 0) {                                                            \
        _Pragma("unroll") for (int m = 0; m < 4; ++m)                           \
            _Pragma("unroll") for (int n = 0; n < 4; ++n)                       \
                acci[m][n] = __builtin_amdgcn_mfma_i32_16x16x64_i8(             \
                    af[m], bf[n], zeroc, 0, 0, 0);                              \
      } else {                                                                  \
        _Pragma("unroll") for (int m = 0; m < 4; ++m)                           \
            _Pragma("unroll") for (int n = 0; n < 4; ++n)                       \
                acci[m][n] = __builtin_amdgcn_mfma_i32_16x16x64_i8(             \
                    af[m], bf[n], acci[m][n], 0, 0, 0);                         \
      }                                                                         \
    }                                                                           \
    _Pragma("unroll") for (int m = 0; m < 4; ++m) {                             \
      const float4 sx4_ = *reinterpret_cast<const float4*>(                     \
          xsl + (kb) * BM + wr * 64 + m * 16 + lhi * 4);                        \
      _Pragma("unroll") for (int r = 0; r < 4; ++r) {                           \
        const float sx_ = ((const float*)&sx4_)[r];                             \
        _Pragma("unroll") for (int n = 0; n < 4; ++n)                           \
            accf[m][n][r] += (float)acci[m][n][r] * sx_;                        \
      }                                                                         \
    }                                                                           \
  }

  // prologue: stage tile 0 + premultiplied scale table; full drain once
  STAGE(0, 0);
#pragma unroll
  for (int i = 0; i < 4; ++i) {
    const int idx = i * 256 + tid;       // 1024 float4 chunks = 32 kb x 128 rows
    const int c = idx >> 5;              // kb index
    const int r4 = idx & 31;             // float4 group within the 128 rows
    float4 v = *reinterpret_cast<const float4*>(
        xsT + (size_t)c * MDIM + brow + r4 * 4);
    const float swc = wsp[bn * KB + c];
    v.x *= swc; v.y *= swc; v.z *= swc; v.w *= swc;
    *reinterpret_cast<float4*>(xsl + c * BM + r4 * 4) = v;
  }
  __syncthreads();   // drains vmcnt(0) + lgkmcnt(0): tile 0 and xsl are ready

  int buf = 0;
  for (int kb = 0; kb < KB - 1; ++kb) {
    STAGE(buf ^ 1, kb + 1);    // async; flies during COMPUTE
    COMPUTE(buf, kb);
    asm volatile("s_waitcnt vmcnt(0)" ::: "memory");
    __builtin_amdgcn_s_barrier();
    buf ^= 1;
  }
  COMPUTE(buf, KB - 1);

  // epilogue: bias + store f32
#pragma unroll
  for (int m = 0; m < 4; ++m) {
#pragma unroll
    for (int r = 0; r < 4; ++r) {
      const int row = brow + wr * 64 + m * 16 + lhi * 4 + r;
#pragma unroll
      for (int n = 0; n < 4; ++n) {
        const int col = bcol + wc * 64 + n * 16 + l15;
        C[(size_t)row * NDIM + col] = accf[m][n][r] + bias[col];
      }
    }
  }
#undef STAGE
#undef COMPUTE
}

extern "C" void kernel_launch(void* const* d_in, const int* in_sizes, int n_in,
                              void* d_out, int out_size, void* d_ws, size_t ws_size,
                              hipStream_t stream) {
  const float* x = (const float*)d_in[0];
  const float* w = (const float*)d_in[1];
  const float* bias = (const float*)d_in[2];
  float* out = (float*)d_out;

  char* base = (char*)d_ws;
  size_t off = 0;
  int8_t* xq = (int8_t*)(base + off); off += (size_t)MDIM * KDIM;          // 32 MB
  int8_t* wq = (int8_t*)(base + off); off += (size_t)NDIM * KDIM;          // 16 MB
  float* xsT = (float*)(base + off); off += (size_t)KB * MDIM * 4;         // 1 MB
  float* wsc = (float*)(base + off);                                       // 4 KB

  quant_x_kernel<<<(MDIM * KB) / 4, 256, 0, stream>>>(x, xq, xsT);
  quant_w_kernel<<<NB * KB, 256, 0, stream>>>(w, wq, wsc);
  gemm_i8_kernel<<<(MDIM / BM) * (NDIM / BN), 256, 0, stream>>>(xq, wq, xsT, wsc, bias, out);
}